// Round 1
// baseline (152.091 us; speedup 1.0000x reference)
//
#include <hip/hip_runtime.h>
#include <stdint.h>

// Problem constants
#define NB 4096   // simclr batch B
#define ND 256    // dim D
#define NN 8192   // num cells N
#define NP 4096   // num pairs P

// sigma = sqrt(1/(0.07*ln2)); stored vectors are normalized * sigma so that
// MFMA dot = sim/(T*ln2)  =>  exp(sim/T) = exp2(dot). sigma^2 = 20.6099253
#define K_SIGMA 4.5398156f
#define LN2F    0.6931471805599453f

typedef __attribute__((ext_vector_type(8))) short short8;
typedef __attribute__((ext_vector_type(4))) float f32x4;

__device__ __forceinline__ float bf2f(uint16_t u) {
  union { uint32_t i; float f; } v; v.i = ((uint32_t)u) << 16; return v.f;
}
__device__ __forceinline__ uint16_t f2bf(float f) {
  union { float f; uint32_t i; } v; v.f = f;
  uint32_t b = v.i;
  b += 0x7FFF + ((b >> 16) & 1);   // RNE
  return (uint16_t)(b >> 16);
}

// ---------------------------------------------------------------------------
// 1) Normalize rows of z1,z2 -> zb[8192][256] bf16 (scaled by sigma),
//    embeddings -> eb[8192][256]. One wave per row.
// ---------------------------------------------------------------------------
__global__ __launch_bounds__(256) void normalize_kernel(
    const float* __restrict__ z1, const float* __restrict__ z2,
    const float* __restrict__ emb,
    uint16_t* __restrict__ zb, uint16_t* __restrict__ eb)
{
  const int w = threadIdx.x >> 6, lane = threadIdx.x & 63;
  const int row = blockIdx.x * 4 + w;  // 0..16383
  const float* src;
  uint16_t* dst;
  if (row < 4096)      { src = z1  + row * 256;          dst = zb + row * 256; }
  else if (row < 8192) { src = z2  + (row - 4096) * 256; dst = zb + row * 256; }
  else                 { src = emb + (row - 8192) * 256; dst = eb + (row - 8192) * 256; }
  float4 v = *reinterpret_cast<const float4*>(src + lane * 4);
  float ss = v.x * v.x + v.y * v.y + v.z * v.z + v.w * v.w;
#pragma unroll
  for (int m = 1; m < 64; m <<= 1) ss += __shfl_xor(ss, m);
  float inv = K_SIGMA / fmaxf(sqrtf(ss), 1e-12f);
  ushort4 o;
  o.x = f2bf(v.x * inv); o.y = f2bf(v.y * inv);
  o.z = f2bf(v.z * inv); o.w = f2bf(v.w * inv);
  *reinterpret_cast<ushort4*>(dst + lane * 4) = o;
}

// ---------------------------------------------------------------------------
// 2) Fused sweep: rowsum of exp2(dot) over all 8192 columns.
//    bid <  512: simclr rows (zb x zb),  rb = bid>>3, col-chunk = bid&7
//    bid >= 512: spatial rows (eb[anchor] x eb)
//    Block: 256 thr = 4 waves; BM=128 (wave owns 32 rows = 2 row-tiles of 16),
//    BN=64 col tile staged in LDS (XOR-swizzled via pre-swizzled global src),
//    K=256 held fully in A-registers. Partial rowsums -> atomicAdd.
// ---------------------------------------------------------------------------
__global__ __launch_bounds__(256) void sweep_kernel(
    const uint16_t* __restrict__ zb, const uint16_t* __restrict__ eb,
    const int* __restrict__ anchor,
    float* __restrict__ rs_z, float* __restrict__ rs_s)
{
  __shared__ __align__(16) uint16_t lds[64 * 256];   // 32 KiB
  const int bid  = blockIdx.x;
  const int tid  = threadIdx.x;
  const int w    = tid >> 6;
  const int lane = tid & 63;

  const bool spatial = (bid >= 512);
  const int sub = spatial ? (bid - 512) : bid;
  const int rb  = sub >> 3;
  const int cc  = sub & 7;
  const uint16_t* __restrict__ Amat = spatial ? eb : zb;
  const uint16_t* __restrict__ Bmat = spatial ? eb : zb;
  float* __restrict__ rs = spatial ? rs_s : rs_z;

  const int row_base = rb * 128 + w * 32;

  // A fragments in registers: 2 row-tiles x 8 k-steps x 8 bf16 (64 VGPR)
  short8 afrag[2][8];
#pragma unroll
  for (int t = 0; t < 2; ++t) {
    int r  = row_base + t * 16 + (lane & 15);
    int sr = spatial ? anchor[r] : r;
    const uint16_t* ap = Amat + sr * 256 + ((lane >> 4) * 8);
#pragma unroll
    for (int ks = 0; ks < 8; ++ks)
      afrag[t][ks] = *reinterpret_cast<const short8*>(ap + ks * 32);
  }

  float rsacc[2][4];
#pragma unroll
  for (int t = 0; t < 2; ++t)
#pragma unroll
    for (int r = 0; r < 4; ++r) rsacc[t][r] = 0.0f;

  const int cbase = cc * 1024;
  const int r_ = tid >> 5;        // staging row within 8-row group (== row&7)
  const int c_ = tid & 31;        // 16B chunk within row
  const int src_chunk = c_ ^ r_;  // inverse-swizzle on the GLOBAL side

  for (int step = 0; step < 16; ++step) {
    const int col0 = cbase + step * 64;
    __syncthreads();   // previous tile's ds_reads done before overwrite
#pragma unroll
    for (int it = 0; it < 8; ++it) {
      const uint16_t* src = Bmat + (col0 + it * 8 + r_) * 256 + src_chunk * 8;
      uint16_t* dst = &lds[(it * 8 + r_) * 256 + c_ * 8];  // linear: byte = it*4096 + tid*16
      __builtin_amdgcn_global_load_lds(
          (const __attribute__((address_space(1))) void*)src,
          (__attribute__((address_space(3))) void*)dst, 16, 0, 0);
    }
    __syncthreads();

    f32x4 acc[2][4];
#pragma unroll
    for (int t = 0; t < 2; ++t)
#pragma unroll
      for (int ct = 0; ct < 4; ++ct) {
        f32x4 z = {0.0f, 0.0f, 0.0f, 0.0f};
        acc[t][ct] = z;
      }

#pragma unroll
    for (int ks = 0; ks < 8; ++ks) {
#pragma unroll
      for (int ct = 0; ct < 4; ++ct) {
        const int brow = ct * 16 + (lane & 15);
        const int ch   = (ks * 4 + (lane >> 4)) ^ (brow & 7);  // swizzled read
        short8 bfrag = *reinterpret_cast<const short8*>(&lds[(brow * 32 + ch) * 8]);
        acc[0][ct] = __builtin_amdgcn_mfma_f32_16x16x32_bf16(afrag[0][ks], bfrag, acc[0][ct], 0, 0, 0);
        acc[1][ct] = __builtin_amdgcn_mfma_f32_16x16x32_bf16(afrag[1][ks], bfrag, acc[1][ct], 0, 0, 0);
      }
    }

    // epilogue: exp2 + accumulate per-lane partial rowsums
#pragma unroll
    for (int t = 0; t < 2; ++t)
#pragma unroll
      for (int ct = 0; ct < 4; ++ct)
#pragma unroll
        for (int r = 0; r < 4; ++r)
          rsacc[t][r] += exp2f(acc[t][ct][r]);
  }

  // C/D layout: col = lane&15, row = (lane>>4)*4 + r  (m89-verified).
  // Sum over the 16 column-lanes (xor within low 4 bits), then atomicAdd.
#pragma unroll
  for (int t = 0; t < 2; ++t)
#pragma unroll
    for (int r = 0; r < 4; ++r) {
      float v = rsacc[t][r];
      v += __shfl_xor(v, 1);
      v += __shfl_xor(v, 2);
      v += __shfl_xor(v, 4);
      v += __shfl_xor(v, 8);
      if ((lane & 15) == 0) {
        int row = row_base + t * 16 + (lane >> 4) * 4 + r;
        atomicAdd(&rs[row], v);
      }
    }
}

// ---------------------------------------------------------------------------
// 3) Finalize: recompute self/pair dots from the SAME bf16 data (so the
//    huge exp2(self) term cancels against the one inside rowsum), emit loss.
//    One wave per row; rows 0..8191 = simclr, 8192..12287 = spatial.
// ---------------------------------------------------------------------------
__global__ __launch_bounds__(256) void finalize_kernel(
    const uint16_t* __restrict__ zb, const uint16_t* __restrict__ eb,
    const int* __restrict__ anchor, const int* __restrict__ neighbor,
    const float* __restrict__ rs_z, const float* __restrict__ rs_s,
    float* __restrict__ loss_z, float* __restrict__ loss_s)
{
  const int w = threadIdx.x >> 6, lane = threadIdx.x & 63;
  const int row = blockIdx.x * 4 + w;   // 0..12287
  const uint16_t *pa, *pb;
  const bool is_z = (row < 8192);
  int idx;
  bool same = false;
  if (is_z) {
    idx = row;
    int pair = (row < 4096) ? row + 4096 : row - 4096;
    pa = zb + row * 256;
    pb = zb + pair * 256;
  } else {
    idx = row - 8192;
    int ai = anchor[idx], ni = neighbor[idx];
    same = (ai == ni);
    pa = eb + ai * 256;
    pb = eb + ni * 256;
  }
  ushort4 ua = *reinterpret_cast<const ushort4*>(pa + lane * 4);
  ushort4 ub = *reinterpret_cast<const ushort4*>(pb + lane * 4);
  float a0 = bf2f(ua.x), a1 = bf2f(ua.y), a2 = bf2f(ua.z), a3 = bf2f(ua.w);
  float b0 = bf2f(ub.x), b1 = bf2f(ub.y), b2 = bf2f(ub.z), b3 = bf2f(ub.w);
  float dd = a0 * a0 + a1 * a1 + a2 * a2 + a3 * a3;  // self-dot (scaled)
  float dn = a0 * b0 + a1 * b1 + a2 * b2 + a3 * b3;  // pair/neighbor dot
#pragma unroll
  for (int m = 1; m < 64; m <<= 1) {
    dd += __shfl_xor(dd, m);
    dn += __shfl_xor(dn, m);
  }
  if (lane == 0) {
    if (is_z) {
      // sum_exp = rowsum - exp(sim_ii); loss = log(sum_exp) - sim_pair/T
      loss_z[idx] = logf(rs_z[idx] - exp2f(dd)) - dn * LN2F;
    } else {
      // S = rowsum - exp(sim_anchor) (+ exp(pos) back if anchor==neighbor)
      float S = rs_s[idx] - exp2f(dd) + (same ? exp2f(dn) : 0.0f);
      loss_s[idx] = logf(S) - dn * LN2F;
    }
  }
}

// ---------------------------------------------------------------------------
// 4) Reduce per-row losses -> out[0] (simclr mean), out[1] (spatial mean)
// ---------------------------------------------------------------------------
__global__ __launch_bounds__(256) void reduce_kernel(
    const float* __restrict__ loss_z, const float* __restrict__ loss_s,
    float* __restrict__ out)
{
  const int which = blockIdx.x;
  const float* src = which ? loss_s : loss_z;
  const int n = which ? 4096 : 8192;
  float s = 0.0f;
  for (int i = threadIdx.x; i < n; i += 256) s += src[i];
#pragma unroll
  for (int m = 1; m < 64; m <<= 1) s += __shfl_xor(s, m);
  __shared__ float ps[4];
  if ((threadIdx.x & 63) == 0) ps[threadIdx.x >> 6] = s;
  __syncthreads();
  if (threadIdx.x == 0)
    out[which] = (ps[0] + ps[1] + ps[2] + ps[3]) * (which ? (1.0f / 4096.0f) : (1.0f / 8192.0f));
}

// ---------------------------------------------------------------------------
extern "C" void kernel_launch(void* const* d_in, const int* in_sizes, int n_in,
                              void* d_out, int out_size, void* d_ws, size_t ws_size,
                              hipStream_t stream) {
  const float* z1      = (const float*)d_in[0];
  const float* z2      = (const float*)d_in[1];
  const float* emb     = (const float*)d_in[2];
  const int*   anchor  = (const int*)d_in[3];
  const int*   neighbor= (const int*)d_in[4];
  float* out = (float*)d_out;

  float* ws      = (float*)d_ws;
  float* rs_z    = ws;              // 8192 f32
  float* rs_s    = ws + 8192;       // 4096 f32
  float* loss_z  = ws + 12288;      // 8192 f32
  float* loss_s  = ws + 20480;      // 4096 f32
  uint16_t* zb   = (uint16_t*)(ws + 24576);   // 8192*256 bf16 (4 MiB)
  uint16_t* eb   = zb + 8192 * 256;           // 8192*256 bf16 (4 MiB)

  // zero only the atomic accumulators (ws is poisoned 0xAA each launch)
  hipMemsetAsync(ws, 0, 12288 * sizeof(float), stream);
  normalize_kernel<<<4096, 256, 0, stream>>>(z1, z2, emb, zb, eb);
  sweep_kernel<<<768, 256, 0, stream>>>(zb, eb, anchor, rs_z, rs_s);
  finalize_kernel<<<3072, 256, 0, stream>>>(zb, eb, anchor, neighbor,
                                            rs_z, rs_s, loss_z, loss_s);
  reduce_kernel<<<2, 256, 0, stream>>>(loss_z, loss_s, out);
}